// Round 11
// baseline (221.473 us; speedup 1.0000x reference)
//
#include <hip/hip_runtime.h>

// IF (integrate-and-fire) SNN forward scan.
// x: [T*B, C, H, W] fp32 viewed as [T=8, slice=4,194,304 floats]; out same shape.
// Per element n: mem=0.5*thr; for t: mem+=x[t][n]; sp=(mem>=thr)?thr:0; mem-=sp.
//
// Ladder (aggregate bench us; kernel ~= agg - 155):
// R1  one-shot f4                      -> 243.8
// R2  ILP=2 + nt st (VGPR 32)          -> 233.8
// R3  persistent + nt ld/st            -> 238.9 (kernel <80)
// R4  normal loads                     -> 258.6 (nt ld = +25%)
// R7  forced  8-deep MLP               -> 232.5
// R8  LDS staging                      -> 246.5 REGRESSED
// R9  forced 16-deep (48 KiB/CU)       -> 222.8
// R10 forced 32-deep (64 KiB/CU)       -> 217.8
//
// Limiter = per-CU outstanding read bytes in distinct dest VGPRs. Gradient
// still paying at 32-deep. R11: 48-deep (ILP=6, 96 KiB/CU), lb(256,2),
// ~225 VGPR (no spill). Last block partial -> uniform branch, clamped loads
// + predicated stores only there. If neutral vs R10 -> knee found, declare
// pattern-intrinsic roofline.

typedef float f4 __attribute__((ext_vector_type(4)));

constexpr int T_STEPS = 8;
constexpr int BLOCK   = 256;
constexpr int ILP     = 6;      // six n-columns per thread -> 48 loads in flight

template <bool GUARD>
__device__ __forceinline__ void if_tile(
    const f4* __restrict__ x, f4* __restrict__ out,
    int i0, int stride4, float thr, float h)
{
    // Load addresses: clamp OOB columns to 0 (harmless re-read) so the issue
    // stream stays full-rate; stores are predicated instead.
    int col[ILP];
#pragma unroll
    for (int j = 0; j < ILP; ++j) {
        int c = i0 + j * BLOCK;
        col[j] = (!GUARD || c < stride4) ? c : 0;
    }

    // 48 independent nt loads; sched_barrier(0) pins them all before any
    // consumption -> 48 distinct f4 dests (192 VGPRs), 12 KiB in flight/thread.
    f4 xt[T_STEPS][ILP];
#pragma unroll
    for (int t = 0; t < T_STEPS; ++t) {
#pragma unroll
        for (int j = 0; j < ILP; ++j) {
            xt[t][j] = __builtin_nontemporal_load(
                x + (size_t)t * stride4 + col[j]);
        }
    }
    __builtin_amdgcn_sched_barrier(0);

    f4 m[ILP];
#pragma unroll
    for (int j = 0; j < ILP; ++j) {
        m[j] = (f4){h, h, h, h};
    }

#pragma unroll
    for (int t = 0; t < T_STEPS; ++t) {
#pragma unroll
        for (int j = 0; j < ILP; ++j) {
            m[j] += xt[t][j];
            f4 s;
#pragma unroll
            for (int k = 0; k < 4; ++k) {
                s[k] = (m[j][k] >= thr) ? thr : 0.0f;
            }
            m[j] -= s;
            if (!GUARD || (i0 + j * BLOCK) < stride4) {
                __builtin_nontemporal_store(
                    s, out + (size_t)t * stride4 + col[j]);
            }
        }
    }
}

__global__ __launch_bounds__(BLOCK, 2) void if_fwd_kernel(
    const f4* __restrict__ x,
    const float* __restrict__ thresh,
    f4* __restrict__ out,
    int stride4)   // float4s per timestep slice (1,048,576)
{
    const int i0    = blockIdx.x * (BLOCK * ILP) + threadIdx.x;
    const float thr = thresh[0];      // wave-uniform -> scalar load
    const float h   = 0.5f * thr;

    if (blockIdx.x < gridDim.x - 1) {        // uniform scalar branch
        if_tile<false>(x, out, i0, stride4, thr, h);   // hot path, no guards
    } else {
        if_tile<true>(x, out, i0, stride4, thr, h);    // tail block only
    }
}

extern "C" void kernel_launch(void* const* d_in, const int* in_sizes, int n_in,
                              void* d_out, int out_size, void* d_ws, size_t ws_size,
                              hipStream_t stream) {
    const float* x      = (const float*)d_in[0];   // [T*B, C, H, W] fp32
    const float* thresh = (const float*)d_in[1];   // scalar threshold (1 elem)
    float* out          = (float*)d_out;

    const int total   = in_sizes[0];       // 33,554,432
    const int stride  = total / T_STEPS;   // 4,194,304 elems per slice
    const int stride4 = stride / 4;        // 1,048,576 float4s per slice

    const int per_block = BLOCK * ILP;     // 1536 f4 per slice per block
    dim3 block(BLOCK);
    dim3 grid((stride4 + per_block - 1) / per_block);   // 683 blocks
    if_fwd_kernel<<<grid, block, 0, stream>>>(
        (const f4*)x, thresh, (f4*)out, stride4);
}

// Round 12
// 217.818 us; speedup vs baseline: 1.0168x; 1.0168x over previous
//
#include <hip/hip_runtime.h>

// IF (integrate-and-fire) SNN forward scan.
// x: [T*B, C, H, W] fp32 viewed as [T=8, slice=4,194,304 floats]; out same shape.
// Per element n: mem=0.5*thr; for t: mem+=x[t][n]; sp=(mem>=thr)?thr:0; mem-=sp.
//
// Final ladder (aggregate bench us; kernel ~= agg - 155):
// R1  one-shot f4, default VGPR=28         -> 243.8  (kernel 90)
// R2  ILP=2 + nt st (VGPR 32)              -> 233.8
// R3  persistent + nt ld/st                -> 238.9
// R4  R3 w/ normal loads                   -> 258.6  (nt LOADS = +25%, locked in)
// R5  SW pipeline (flattened at VGPR 32)   -> 235.6
// R7  forced  8-deep MLP (sched_barrier)   -> 232.5
// R8  LDS staging (global_load_lds)        -> 246.5  REGRESSED
// R9  forced 16-deep (48 KiB/CU outst.)    -> 222.8
// R10 forced 32-deep (64 KiB/CU outst.)    -> 217.8  BEST
// R11 forced 48-deep (96 KiB/CU, 683 blk)  -> 221.5  REGRESSED (knee / imbalance)
//
// ROOT CAUSE of the whole session: the compiler's default max-occupancy
// register budget (VGPR=32) silently serialized the load stream in every
// naive variant. Fix = launch_bounds VGPR headroom + sched_barrier(0) to pin
// N independent nt loads in distinct dest registers. Depth knee at 32.
// Residual gap to the 43-us copy roofline (~4.3 vs 6.3 TB/s) is
// pattern-intrinsic: 16 live 16-MiB-strided streams/block x 512 resident
// blocks ~ 8K concurrent DRAM row-streams -> row-activate-bound latency ~2x
// a contiguous copy; no CU-side lever moved it (structure, LDS, contiguity
// all tested and neutral/regressed).
//
// R12 = exact revert to R10 (measured optimum).

typedef float f4 __attribute__((ext_vector_type(4)));

constexpr int T_STEPS = 8;
constexpr int BLOCK   = 256;
constexpr int ILP     = 4;      // four n-columns per thread -> 32 loads in flight

__global__ __launch_bounds__(BLOCK, 2) void if_fwd_kernel(
    const f4* __restrict__ x,
    const float* __restrict__ thresh,
    f4* __restrict__ out,
    int stride4)   // float4s per timestep slice (1,048,576)
{
    const int i0 = blockIdx.x * (BLOCK * ILP) + threadIdx.x;

    const float thr = thresh[0];      // wave-uniform -> scalar load
    const float h   = 0.5f * thr;

    // 32 independent nt loads; sched_barrier(0) pins them all before any
    // consumption -> 32 distinct f4 dests (128 VGPRs), 8 KiB in flight/thread.
    f4 xt[T_STEPS][ILP];
#pragma unroll
    for (int t = 0; t < T_STEPS; ++t) {
#pragma unroll
        for (int j = 0; j < ILP; ++j) {
            xt[t][j] = __builtin_nontemporal_load(
                x + (size_t)t * stride4 + i0 + j * BLOCK);
        }
    }
    __builtin_amdgcn_sched_barrier(0);

    f4 m[ILP];
#pragma unroll
    for (int j = 0; j < ILP; ++j) {
        m[j] = (f4){h, h, h, h};
    }

#pragma unroll
    for (int t = 0; t < T_STEPS; ++t) {
#pragma unroll
        for (int j = 0; j < ILP; ++j) {
            m[j] += xt[t][j];
            f4 s;
#pragma unroll
            for (int k = 0; k < 4; ++k) {
                s[k] = (m[j][k] >= thr) ? thr : 0.0f;
            }
            m[j] -= s;
            __builtin_nontemporal_store(
                s, out + (size_t)t * stride4 + i0 + j * BLOCK);
        }
    }
}

extern "C" void kernel_launch(void* const* d_in, const int* in_sizes, int n_in,
                              void* d_out, int out_size, void* d_ws, size_t ws_size,
                              hipStream_t stream) {
    const float* x      = (const float*)d_in[0];   // [T*B, C, H, W] fp32
    const float* thresh = (const float*)d_in[1];   // scalar threshold (1 elem)
    float* out          = (float*)d_out;

    const int total   = in_sizes[0];       // 33,554,432
    const int stride  = total / T_STEPS;   // 4,194,304 elems per slice
    const int stride4 = stride / 4;        // 1,048,576 float4s per slice

    dim3 block(BLOCK);
    dim3 grid(stride4 / (BLOCK * ILP));    // 1024 blocks = 4 per CU, balanced
    if_fwd_kernel<<<grid, block, 0, stream>>>(
        (const f4*)x, thresh, (f4*)out, stride4);
}